// Round 4
// baseline (727.649 us; speedup 1.0000x reference)
//
#include <hip/hip_runtime.h>

#define NB 32
#define NS 2048
#define ND 1024

typedef unsigned short u16;
typedef unsigned int u32;
typedef __attribute__((ext_vector_type(8))) short bf16x8;
typedef __attribute__((ext_vector_type(4))) float f32x4;

__device__ __forceinline__ u16 f2bf(float f) {
    u32 u = __float_as_uint(f);
    u32 r = u + 0x7fffu + ((u >> 16) & 1u);
    return (u16)(r >> 16);
}
__device__ __forceinline__ float bf2f(u32 lo16) {
    return __uint_as_float(lo16 << 16);
}
__device__ __forceinline__ void gload_lds16(const void* g, void* l) {
    __builtin_amdgcn_global_load_lds((const __attribute__((address_space(1))) void*)g,
                                     (__attribute__((address_space(3))) void*)l, 16, 0, 0);
}

// ---------------- kernel 1: masked column sum + bf16 swizzled tile image stash
// image layout per tile (128 KiB): byte[i*2048 + ((t*8) ^ ((i&7)<<4))] = bf16 pair (cols 4t..4t+3)
template <bool DO_STASH>
__global__ void k_prep(const float* __restrict__ X, const int* __restrict__ len,
                       float* __restrict__ sumX, u16* __restrict__ stash) {
    int b = blockIdx.x >> 5, c = blockIdx.x & 31;
    int L = len[b];
    int s0 = c * 64;
    if (s0 >= L) return;
    int n = min(64, L - s0);
    int t = threadIdx.x;
    const float4* base = (const float4*)(X + (size_t)b * NS * ND + (size_t)s0 * ND) + t;
    char* img = (char*)stash + ((size_t)blockIdx.x << 17);
    float4 acc = {0.f, 0.f, 0.f, 0.f};
    for (int i = 0; i < n; ++i) {
        float4 x = base[i * (ND / 4)];
        acc.x += x.x; acc.y += x.y; acc.z += x.z; acc.w += x.w;
        if constexpr (DO_STASH) {
            u32 lo = (u32)f2bf(x.x) | ((u32)f2bf(x.y) << 16);
            u32 hi = (u32)f2bf(x.z) | ((u32)f2bf(x.w) << 16);
            u32 off = (u32)i * 2048u + (((u32)t * 8u) ^ (((u32)(i & 7)) << 4));
            *(uint2*)(img + off) = make_uint2(lo, hi);
        }
    }
    if constexpr (DO_STASH) {
        for (int i = n; i < 64; ++i) {
            u32 off = (u32)i * 2048u + (((u32)t * 8u) ^ (((u32)(i & 7)) << 4));
            *(uint2*)(img + off) = make_uint2(0u, 0u);
        }
    }
    float* o = sumX + b * ND + t * 4;
    atomicAdd(o + 0, acc.x); atomicAdd(o + 1, acc.y);
    atomicAdd(o + 2, acc.z); atomicAdd(o + 3, acc.w);
}

// ---------------- kernel 2: pack Wl -> bf16 MFMA B-fragments (lane-ordered, 1KiB/frag)
// f = nc*128 + j*32 + kc*4 + ks covers B[k=kc*128+ks*32+(l>>4)*8+e][n=nc*64+j*16+(l&15)]
__global__ void k_pack(const float* __restrict__ Wl, u16* __restrict__ pack) {
    int t = threadIdx.x;
    int f = blockIdx.x * 4 + (t >> 6);
    int lane = t & 63;
    int ks = f & 3, kc = (f >> 2) & 7, j = (f >> 5) & 3, nc = f >> 7;
    int n = nc * 64 + j * 16 + (lane & 15);
    int k0 = kc * 128 + ks * 32 + ((lane >> 4) << 3);
    u16 tmp[8];
    #pragma unroll
    for (int e = 0; e < 8; ++e)
        tmp[e] = f2bf(Wl[(size_t)(k0 + e) * ND + n]);
    *(uint4*)(pack + (size_t)f * 512 + lane * 8) = *(const uint4*)tmp;
}

// ---------------- kernel 3: yg[b,e] += sum_{d in d-block} sumX[b,d] * Wg[d,e]
// grid 128 = 16 e-blocks x 8 d-blocks; yg pre-zeroed
__global__ void k_gproj(const float* __restrict__ sumX, const float* __restrict__ Wg,
                        float* __restrict__ yg) {
    __shared__ float sx[32][64];
    int t = threadIdx.x;
    int eb = blockIdx.x & 15, db = blockIdx.x >> 4;
    int e = eb * 64 + (t & 63);
    int bg = t >> 6;
    float acc[8] = {0.f,0.f,0.f,0.f,0.f,0.f,0.f,0.f};
    for (int d0 = db * 128; d0 < db * 128 + 128; d0 += 64) {
        __syncthreads();
        #pragma unroll
        for (int j = 0; j < 8; ++j) {
            int idx = t + j * 256;
            sx[idx >> 6][idx & 63] = sumX[(idx >> 6) * ND + d0 + (idx & 63)];
        }
        __syncthreads();
        for (int dd = 0; dd < 64; ++dd) {
            float wv = Wg[(size_t)(d0 + dd) * ND + e];
            #pragma unroll
            for (int j = 0; j < 8; ++j) acc[j] += wv * sx[bg * 8 + j][dd];
        }
    }
    #pragma unroll
    for (int j = 0; j < 8; ++j) atomicAdd(&yg[(bg * 8 + j) * ND + e], acc[j]);
}

// ---------------- kernel 4: gp[b,:] = l2norm(yg[b,:])
__global__ void k_gnorm(const float* __restrict__ yg, float* __restrict__ gp) {
    int b = blockIdx.x, t = threadIdx.x;
    float4 y = ((const float4*)(yg + (size_t)b * ND))[t];
    float ss = y.x * y.x + y.y * y.y + y.z * y.z + y.w * y.w;
    #pragma unroll
    for (int o = 32; o; o >>= 1) ss += __shfl_down(ss, o);
    __shared__ float wsum[4];
    if ((t & 63) == 0) wsum[t >> 6] = ss;
    __syncthreads();
    float tot = wsum[0] + wsum[1] + wsum[2] + wsum[3];
    float sc = 1.f / sqrtf(fmaxf(tot, 1e-12f));
    float4 g = {y.x * sc, y.y * sc, y.z * sc, y.w * sc};
    ((float4*)(gp + (size_t)b * ND))[t] = g;
}

// ---------------- kernel 5: main fused kernel, 64-token tiles, 4 waves
// wave w: all 4 row-blocks x nc in {w,w+4,w+8,w+12}; B-frags direct from L2 pack;
// dot fused into phase B via dot[m] = y[m,:] . gp[b,:]
template <bool STASH>
__global__ __launch_bounds__(256, 1) void k_main(
    const float* __restrict__ X, const int* __restrict__ len,
    const u16* __restrict__ stash, const u16* __restrict__ pack,
    const float* __restrict__ gp, float* __restrict__ out) {
    __shared__ u16 Xs[64 * 1024];       // 128 KiB, bf16, XOR-swizzled (byte bits 4-6 ^= row&7)
    __shared__ float gp_s[1024];
    __shared__ float norm2_s[4][64];
    __shared__ float dot_s[4][64];
    __shared__ float att_s[64];

    int b = blockIdx.x >> 5;
    int tile = blockIdx.x & 31;
    int L = len[b];
    int s0 = tile * 64;
    if (s0 >= L) return;
    int valid = min(64, L - s0);
    int t = threadIdx.x;
    int lane = t & 63, w = t >> 6;

    // ---- phase A: stage X tile (bf16, swizzled) + gp, zero partials
    if constexpr (STASH) {
        // stash image is byte-identical to desired LDS content -> pure linear copy
        const char* gsrc = (const char*)stash + ((size_t)blockIdx.x << 17)
                         + (size_t)w * 32768 + (size_t)lane * 16;
        char* ldst = (char*)Xs + w * 32768;   // wave-uniform base; HW adds lane*16
        #pragma unroll
        for (int i = 0; i < 32; ++i)
            gload_lds16(gsrc + i * 1024, ldst + i * 1024);
    } else {
        const float* Xb = X + (size_t)b * NS * ND + (size_t)s0 * ND;
        for (int i = 0; i < 64; ++i) {
            float4 x = {0.f, 0.f, 0.f, 0.f};
            if (i < valid) x = ((const float4*)(Xb + (size_t)i * ND))[t];
            u32 lo = (u32)f2bf(x.x) | ((u32)f2bf(x.y) << 16);
            u32 hi = (u32)f2bf(x.z) | ((u32)f2bf(x.w) << 16);
            u32 off = (u32)i * 2048u + (((u32)t * 8u) ^ (((u32)(i & 7)) << 4));
            *(uint2*)((char*)Xs + off) = make_uint2(lo, hi);
        }
    }
    for (int jj = t; jj < 1024; jj += 256) gp_s[jj] = gp[b * ND + jj];
    ((float*)norm2_s)[t] = 0.f;
    ((float*)dot_s)[t] = 0.f;
    __syncthreads();

    // ---- phase B: y = Xs @ Wl per nc-chunk; accumulate sum(y^2) and sum(y*gp).
    // No barriers inside the loop nest.
    for (int q = 0; q < 4; ++q) {
        int nc = w + q * 4;
        const u16* pb = pack + (size_t)nc * 128 * 512;
        f32x4 acc[4][4];
        #pragma unroll
        for (int rb = 0; rb < 4; ++rb)
            #pragma unroll
            for (int j = 0; j < 4; ++j) acc[rb][j] = (f32x4){0.f, 0.f, 0.f, 0.f};

        #pragma unroll 2
        for (int kc = 0; kc < 8; ++kc) {
            #pragma unroll
            for (int ks = 0; ks < 4; ++ks) {
                int kbyte = kc * 256 + ks * 64 + ((lane >> 4) << 4);
                bf16x8 a[4];
                #pragma unroll
                for (int rb = 0; rb < 4; ++rb) {
                    int row = (rb << 4) + (lane & 15);
                    a[rb] = *(const bf16x8*)((const char*)Xs + row * 2048 +
                                             (kbyte ^ ((row & 7) << 4)));
                }
                #pragma unroll
                for (int j = 0; j < 4; ++j) {
                    bf16x8 bb = *(const bf16x8*)(pb + ((size_t)(j * 32 + kc * 4 + ks)) * 512 + lane * 8);
                    #pragma unroll
                    for (int rb = 0; rb < 4; ++rb)
                        acc[rb][j] = __builtin_amdgcn_mfma_f32_16x16x32_bf16(a[rb], bb, acc[rb][j], 0, 0, 0);
                }
            }
        }
        // C layout: col n-local = lane&15, row = rb*16 + (lane>>4)*4 + reg
        float gpv[4];
        #pragma unroll
        for (int j = 0; j < 4; ++j) gpv[j] = gp_s[nc * 64 + j * 16 + (lane & 15)];
        #pragma unroll
        for (int rb = 0; rb < 4; ++rb) {
            #pragma unroll
            for (int reg = 0; reg < 4; ++reg) {
                float s = 0.f, d = 0.f;
                #pragma unroll
                for (int j = 0; j < 4; ++j) {
                    float y = acc[rb][j][reg];
                    s += y * y;
                    d += y * gpv[j];
                }
                s += __shfl_xor(s, 1); d += __shfl_xor(d, 1);
                s += __shfl_xor(s, 2); d += __shfl_xor(d, 2);
                s += __shfl_xor(s, 4); d += __shfl_xor(d, 4);
                s += __shfl_xor(s, 8); d += __shfl_xor(d, 8);
                if ((lane & 15) == 0) {
                    int row = (rb << 4) + ((lane >> 4) << 2) + reg;
                    norm2_s[w][row] += s;
                    dot_s[w][row] += d;
                }
            }
        }
    }
    __syncthreads();

    // ---- phase C: attention = dot * rsqrt(max(norm2, eps))
    if (t < 64) {
        float n2 = norm2_s[0][t] + norm2_s[1][t] + norm2_s[2][t] + norm2_s[3][t];
        float dp = dot_s[0][t] + dot_s[1][t] + dot_s[2][t] + dot_s[3][t];
        att_s[t] = dp / sqrtf(fmaxf(n2, 1e-12f));
    }
    __syncthreads();

    // ---- phase D: out[b,:] += sum_i att[i] * x_bf16[i,:]  (from LDS)
    {
        float4 acc4 = {0.f, 0.f, 0.f, 0.f};
        for (int i = 0; i < valid; ++i) {
            float a = att_s[i];
            u32 off = (u32)i * 2048u + (((u32)t * 8u) ^ (((u32)(i & 7)) << 4));
            uint2 raw = *(const uint2*)((const char*)Xs + off);
            acc4.x += a * bf2f(raw.x & 0xffffu);
            acc4.y += a * __uint_as_float(raw.x & 0xffff0000u);
            acc4.z += a * bf2f(raw.y & 0xffffu);
            acc4.w += a * __uint_as_float(raw.y & 0xffff0000u);
        }
        float* o = out + b * ND + t * 4;
        atomicAdd(o + 0, acc4.x); atomicAdd(o + 1, acc4.y);
        atomicAdd(o + 2, acc4.z); atomicAdd(o + 3, acc4.w);
    }
}

extern "C" void kernel_launch(void* const* d_in, const int* in_sizes, int n_in,
                              void* d_out, int out_size, void* d_ws, size_t ws_size,
                              hipStream_t stream) {
    (void)in_sizes; (void)n_in; (void)out_size;
    const float* X  = (const float*)d_in[0];
    const int* len  = (const int*)d_in[1];
    const float* Wg = (const float*)d_in[2];
    const float* Wl = (const float*)d_in[3];
    float* out = (float*)d_out;

    char* ws = (char*)d_ws;
    float* sumX = (float*)(ws + 0);        // 128 KiB
    float* yg   = (float*)(ws + 131072);   // 128 KiB (contiguous with sumX for one memset)
    float* gp   = (float*)(ws + 262144);   // 128 KiB
    u16*   pack = (u16*)(ws + 393216);     // 2 MiB
    u16*   stash= (u16*)(ws + 2490368);    // 128 MiB (tile images)
    const size_t need = 2490368ull + (size_t)NB * 32 * 131072ull;
    int use_stash = ws_size >= need;

    hipMemsetAsync(sumX, 0, 2 * NB * ND * sizeof(float), stream);  // sumX + yg
    hipMemsetAsync(out, 0, NB * ND * sizeof(float), stream);

    if (use_stash)
        k_prep<true> <<<NB * 32, 256, 0, stream>>>(X, len, sumX, stash);
    else
        k_prep<false><<<NB * 32, 256, 0, stream>>>(X, len, sumX, stash);
    k_pack <<<512, 256, 0, stream>>>(Wl, pack);
    k_gproj<<<128, 256, 0, stream>>>(sumX, Wg, yg);
    k_gnorm<<<NB, 256, 0, stream>>>(yg, gp);
    if (use_stash)
        k_main<true> <<<NB * 32, 256, 0, stream>>>(X, len, stash, pack, gp, out);
    else
        k_main<false><<<NB * 32, 256, 0, stream>>>(X, len, stash, pack, gp, out);
}

// Round 9
// 604.961 us; speedup vs baseline: 1.2028x; 1.2028x over previous
//
#include <hip/hip_runtime.h>

#define NB 32
#define NS 2048
#define ND 1024

typedef unsigned short u16;
typedef unsigned int u32;
typedef __attribute__((ext_vector_type(8))) short bf16x8;
typedef __attribute__((ext_vector_type(4))) float f32x4;

__device__ __forceinline__ u16 f2bf(float f) {
    u32 u = __float_as_uint(f);
    u32 r = u + 0x7fffu + ((u >> 16) & 1u);
    return (u16)(r >> 16);
}

// ---------------- kernel 1: masked column sum + bf16 A-fragment-packed stash
// tile stash = 128 frags x 1KiB. frag (kk, rb) at (kk*4+rb)*512 u16.
// frag elem: lane l, e: row = rb*16+(l&15), k = kk*32 + (l>>4)*8 + e
// thread t covers k = 4t..4t+3 of every row i: kk = t>>3, l>>4 = (t>>1)&3, e0 = (t&1)*4
template <bool DO_STASH>
__global__ void k_prep(const float* __restrict__ X, const int* __restrict__ len,
                       float* __restrict__ sumX, u16* __restrict__ stash) {
    int b = blockIdx.x >> 5, c = blockIdx.x & 31;
    int L = len[b];
    int s0 = c * 64;
    if (s0 >= L) return;
    int n = min(64, L - s0);
    int t = threadIdx.x;
    const float4* base = (const float4*)(X + (size_t)b * NS * ND + (size_t)s0 * ND) + t;
    u16* tb = stash + ((size_t)blockIdx.x << 16)
            + (size_t)(t >> 3) * 2048 + (((t >> 1) & 3) << 7) + ((t & 1) << 2);
    float4 acc = {0.f, 0.f, 0.f, 0.f};
    for (int i = 0; i < n; ++i) {
        float4 x = base[i * (ND / 4)];
        acc.x += x.x; acc.y += x.y; acc.z += x.z; acc.w += x.w;
        if constexpr (DO_STASH) {
            u32 lo = (u32)f2bf(x.x) | ((u32)f2bf(x.y) << 16);
            u32 hi = (u32)f2bf(x.z) | ((u32)f2bf(x.w) << 16);
            *(uint2*)(tb + (i >> 4) * 512 + (i & 15) * 8) = make_uint2(lo, hi);
        }
    }
    if constexpr (DO_STASH) {
        for (int i = n; i < 64; ++i)
            *(uint2*)(tb + (i >> 4) * 512 + (i & 15) * 8) = make_uint2(0u, 0u);
    }
    float* o = sumX + b * ND + t * 4;
    atomicAdd(o + 0, acc.x); atomicAdd(o + 1, acc.y);
    atomicAdd(o + 2, acc.z); atomicAdd(o + 3, acc.w);
}

// ---------------- kernel 2: pack Wl -> bf16 MFMA B-fragments (lane-ordered, 1KiB/frag)
// f = nc*128 + kk*4 + j covers B[k = kk*32 + (l>>4)*8 + e][n = nc*64 + j*16 + (l&15)]
__global__ void k_pack(const float* __restrict__ Wl, u16* __restrict__ pack) {
    int t = threadIdx.x;
    int f = blockIdx.x * 4 + (t >> 6);
    int lane = t & 63;
    int j = f & 3, kk = (f >> 2) & 31, nc = f >> 7;
    int n = nc * 64 + j * 16 + (lane & 15);
    int k0 = kk * 32 + ((lane >> 4) << 3);
    u16 tmp[8];
    #pragma unroll
    for (int e = 0; e < 8; ++e)
        tmp[e] = f2bf(Wl[(size_t)(k0 + e) * ND + n]);
    *(uint4*)(pack + (size_t)f * 512 + lane * 8) = *(const uint4*)tmp;
}

// ---------------- kernel 3: yg[b,e] += partial over d-block (grid 128 = 16 e x 8 d)
__global__ void k_gproj(const float* __restrict__ sumX, const float* __restrict__ Wg,
                        float* __restrict__ yg) {
    __shared__ float sx[32][64];
    int t = threadIdx.x;
    int eb = blockIdx.x & 15, db = blockIdx.x >> 4;
    int e = eb * 64 + (t & 63);
    int bg = t >> 6;
    float acc[8] = {0.f,0.f,0.f,0.f,0.f,0.f,0.f,0.f};
    for (int d0 = db * 128; d0 < db * 128 + 128; d0 += 64) {
        __syncthreads();
        #pragma unroll
        for (int j = 0; j < 8; ++j) {
            int idx = t + j * 256;
            sx[idx >> 6][idx & 63] = sumX[(idx >> 6) * ND + d0 + (idx & 63)];
        }
        __syncthreads();
        for (int dd = 0; dd < 64; ++dd) {
            float wv = Wg[(size_t)(d0 + dd) * ND + e];
            #pragma unroll
            for (int j = 0; j < 8; ++j) acc[j] += wv * sx[bg * 8 + j][dd];
        }
    }
    #pragma unroll
    for (int j = 0; j < 8; ++j) atomicAdd(&yg[(bg * 8 + j) * ND + e], acc[j]);
}

// ---------------- kernel 4: gp[b,:] = l2norm(yg[b,:])
__global__ void k_gnorm(const float* __restrict__ yg, float* __restrict__ gp) {
    int b = blockIdx.x, t = threadIdx.x;
    float4 y = ((const float4*)(yg + (size_t)b * ND))[t];
    float ss = y.x * y.x + y.y * y.y + y.z * y.z + y.w * y.w;
    #pragma unroll
    for (int o = 32; o; o >>= 1) ss += __shfl_down(ss, o);
    __shared__ float wsum[4];
    if ((t & 63) == 0) wsum[t >> 6] = ss;
    __syncthreads();
    float tot = wsum[0] + wsum[1] + wsum[2] + wsum[3];
    float sc = 1.f / sqrtf(fmaxf(tot, 1e-12f));
    float4 g = {y.x * sc, y.y * sc, y.z * sc, y.w * sc};
    ((float4*)(gp + (size_t)b * ND))[t] = g;
}

// ---------------- kernel 5: main fused kernel. NO big LDS; frags direct from global.
// wave w: nc in {w, w+4, w+8, w+12}; per (kk): 4 A-frags (shared) x 4 B-frags -> 16 MFMA
template <bool STASH>
__global__ __launch_bounds__(256, 3) void k_main(
    const float* __restrict__ X, const int* __restrict__ len,
    const u16* __restrict__ stash, const u16* __restrict__ pack,
    const float* __restrict__ gp, float* __restrict__ out) {
    __shared__ float gp_s[1024];
    __shared__ float norm2_s[4][64];
    __shared__ float dot_s[4][64];
    __shared__ float att_s[64];

    int b = blockIdx.x >> 5;
    int tile = blockIdx.x & 31;
    int L = len[b];
    int s0 = tile * 64;
    if (s0 >= L) return;
    int valid = min(64, L - s0);
    int t = threadIdx.x;
    int lane = t & 63, w = t >> 6;

    for (int jj = t; jj < 1024; jj += 256) gp_s[jj] = gp[b * ND + jj];
    ((float*)norm2_s)[t] = 0.f;
    ((float*)dot_s)[t] = 0.f;
    __syncthreads();

    const u16* ta = stash + ((size_t)blockIdx.x << 16) + lane * 8;
    const float* Xb = X + (size_t)b * NS * ND + (size_t)s0 * ND;

    // ---- phase B: y = X_tile @ Wl per nc; accumulate sum(y^2), sum(y*gp)
    for (int q = 0; q < 4; ++q) {
        int nc = w + q * 4;
        const u16* pb = pack + (size_t)nc * 65536 + lane * 8;
        f32x4 acc[4][4];
        #pragma unroll
        for (int rb = 0; rb < 4; ++rb)
            #pragma unroll
            for (int j = 0; j < 4; ++j) acc[rb][j] = (f32x4){0.f, 0.f, 0.f, 0.f};

        #pragma unroll 2
        for (int kk = 0; kk < 32; ++kk) {
            bf16x8 a[4], bb[4];
            if constexpr (STASH) {
                #pragma unroll
                for (int rb = 0; rb < 4; ++rb)
                    a[rb] = *(const bf16x8*)(ta + (kk * 4 + rb) * 512);
            } else {
                int kb = kk * 32 + ((lane >> 4) << 3);
                #pragma unroll
                for (int rb = 0; rb < 4; ++rb) {
                    int row = (rb << 4) + (lane & 15);
                    bf16x8 av = {0,0,0,0,0,0,0,0};
                    if (row < valid) {
                        float4 x0 = *(const float4*)(Xb + (size_t)row * ND + kb);
                        float4 x1 = *(const float4*)(Xb + (size_t)row * ND + kb + 4);
                        av[0] = (short)f2bf(x0.x); av[1] = (short)f2bf(x0.y);
                        av[2] = (short)f2bf(x0.z); av[3] = (short)f2bf(x0.w);
                        av[4] = (short)f2bf(x1.x); av[5] = (short)f2bf(x1.y);
                        av[6] = (short)f2bf(x1.z); av[7] = (short)f2bf(x1.w);
                    }
                    a[rb] = av;
                }
            }
            #pragma unroll
            for (int j = 0; j < 4; ++j)
                bb[j] = *(const bf16x8*)(pb + (kk * 4 + j) * 512);
            #pragma unroll
            for (int j = 0; j < 4; ++j)
                #pragma unroll
                for (int rb = 0; rb < 4; ++rb)
                    acc[rb][j] = __builtin_amdgcn_mfma_f32_16x16x32_bf16(a[rb], bb[j], acc[rb][j], 0, 0, 0);
        }
        // C layout: col n-local = lane&15, row = rb*16 + (lane>>4)*4 + reg
        float gpv[4];
        #pragma unroll
        for (int j = 0; j < 4; ++j) gpv[j] = gp_s[nc * 64 + j * 16 + (lane & 15)];
        #pragma unroll
        for (int rb = 0; rb < 4; ++rb) {
            #pragma unroll
            for (int reg = 0; reg < 4; ++reg) {
                float s = 0.f, d = 0.f;
                #pragma unroll
                for (int j = 0; j < 4; ++j) {
                    float y = acc[rb][j][reg];
                    s += y * y;
                    d += y * gpv[j];
                }
                s += __shfl_xor(s, 1); d += __shfl_xor(d, 1);
                s += __shfl_xor(s, 2); d += __shfl_xor(d, 2);
                s += __shfl_xor(s, 4); d += __shfl_xor(d, 4);
                s += __shfl_xor(s, 8); d += __shfl_xor(d, 8);
                if ((lane & 15) == 0) {
                    int row = (rb << 4) + ((lane >> 4) << 2) + reg;
                    norm2_s[w][row] += s;
                    dot_s[w][row] += d;
                }
            }
        }
    }
    __syncthreads();

    // ---- phase C: attention = dot * rsqrt(max(norm2, eps))
    if (t < 64) {
        float n2 = norm2_s[0][t] + norm2_s[1][t] + norm2_s[2][t] + norm2_s[3][t];
        float dp = dot_s[0][t] + dot_s[1][t] + dot_s[2][t] + dot_s[3][t];
        att_s[t] = dp / sqrtf(fmaxf(n2, 1e-12f));
    }
    __syncthreads();

    // ---- phase D: out[b,:] += sum_i att[i] * X[b,s0+i,:]  (fp32, coalesced)
    {
        float4 acc4 = {0.f, 0.f, 0.f, 0.f};
        #pragma unroll 4
        for (int i = 0; i < valid; ++i) {
            float a = att_s[i];
            float4 x = ((const float4*)(Xb + (size_t)i * ND))[t];
            acc4.x += a * x.x; acc4.y += a * x.y; acc4.z += a * x.z; acc4.w += a * x.w;
        }
        float* o = out + b * ND + t * 4;
        atomicAdd(o + 0, acc4.x); atomicAdd(o + 1, acc4.y);
        atomicAdd(o + 2, acc4.z); atomicAdd(o + 3, acc4.w);
    }
}

extern "C" void kernel_launch(void* const* d_in, const int* in_sizes, int n_in,
                              void* d_out, int out_size, void* d_ws, size_t ws_size,
                              hipStream_t stream) {
    (void)in_sizes; (void)n_in; (void)out_size;
    const float* X  = (const float*)d_in[0];
    const int* len  = (const int*)d_in[1];
    const float* Wg = (const float*)d_in[2];
    const float* Wl = (const float*)d_in[3];
    float* out = (float*)d_out;

    char* ws = (char*)d_ws;
    float* sumX = (float*)(ws + 0);        // 128 KiB
    float* yg   = (float*)(ws + 131072);   // 128 KiB (contiguous with sumX: one memset)
    float* gp   = (float*)(ws + 262144);   // 128 KiB
    u16*   pack = (u16*)(ws + 393216);     // 2 MiB
    u16*   stash= (u16*)(ws + 2490368);    // 128 MiB (A-frag tile images)
    const size_t need = 2490368ull + (size_t)NB * 32 * 131072ull;
    int use_stash = ws_size >= need;

    hipMemsetAsync(sumX, 0, 2 * NB * ND * sizeof(float), stream);  // sumX + yg
    hipMemsetAsync(out, 0, NB * ND * sizeof(float), stream);

    if (use_stash)
        k_prep<true> <<<NB * 32, 256, 0, stream>>>(X, len, sumX, stash);
    else
        k_prep<false><<<NB * 32, 256, 0, stream>>>(X, len, sumX, stash);
    k_pack <<<512, 256, 0, stream>>>(Wl, pack);
    k_gproj<<<128, 256, 0, stream>>>(sumX, Wg, yg);
    k_gnorm<<<NB, 256, 0, stream>>>(yg, gp);
    if (use_stash)
        k_main<true> <<<NB * 32, 256, 0, stream>>>(X, len, stash, pack, gp, out);
    else
        k_main<false><<<NB * 32, 256, 0, stream>>>(X, len, stash, pack, gp, out);
}